// Round 3
// baseline (491.861 us; speedup 1.0000x reference)
//
#include <hip/hip_runtime.h>
#include <stdint.h>

// SOM update: x (1024 f32), weights (65536x1024 f32), locations (65536 i32), it (1 i32)
// out: new_weights (65536x1024 f32)

#define N_ROWS 65536
#define DIM    1024
#define EPS    1e-6f
#define NITERF 100.0f
#define ALPHA  0.3f
#define SIGMA  32768.0f

// ---- dist kernel geometry ----
#define DIST_BLOCKS   1024
#define ROWS_PER_WAVE (N_ROWS / (DIST_BLOCKS * 4))   // 16
#define BATCH         4                              // rows reduced together (ILP)

// ---- update kernel geometry ----
#define UPD_BLOCKS    2048
#define ROWS_PER_UBLK (N_ROWS / UPD_BLOCKS)          // 32 rows, contiguous chunk per block

typedef float nfloat4 __attribute__((ext_vector_type(4)));  // native vec for nontemporal builtin

// accumulate 4 squared diffs (same order as the passing baseline -> identical numerics)
#define ACC4(XX, WW) \
    t = XX.x - WW.x + EPS; s = fmaf(t, t, s); \
    t = XX.y - WW.y + EPS; s = fmaf(t, t, s); \
    t = XX.z - WW.z + EPS; s = fmaf(t, t, s); \
    t = XX.w - WW.w + EPS; s = fmaf(t, t, s);

// ---------------- Kernel 1: per-row distance + per-block argmin (batched ILP) ----------------
__global__ __launch_bounds__(256) void som_dist(
    const float* __restrict__ x,
    const float* __restrict__ w,
    unsigned long long* __restrict__ part)
{
    const int lane = threadIdx.x & 63;
    const int wave = threadIdx.x >> 6;
    const int waveRow0 = (blockIdx.x * 4 + wave) * ROWS_PER_WAVE;

    const float4* xv4 = (const float4*)x;
    // hoist x fragment (cols p*64+lane) into registers once
    const float4 xx0 = xv4[0 * 64 + lane];
    const float4 xx1 = xv4[1 * 64 + lane];
    const float4 xx2 = xv4[2 * 64 + lane];
    const float4 xx3 = xv4[3 * 64 + lane];

    unsigned long long best = ~0ull;

    for (int b = 0; b < ROWS_PER_WAVE; b += BATCH) {
        float acc[BATCH];
        #pragma unroll
        for (int r = 0; r < BATCH; ++r) {
            const int row = waveRow0 + b + r;
            const float4* wr = (const float4*)(w + (size_t)row * DIM);
            float4 w0 = wr[0 * 64 + lane];
            float4 w1 = wr[1 * 64 + lane];
            float4 w2 = wr[2 * 64 + lane];
            float4 w3 = wr[3 * 64 + lane];
            float s = 0.0f, t;
            ACC4(xx0, w0)
            ACC4(xx1, w1)
            ACC4(xx2, w2)
            ACC4(xx3, w3)
            acc[r] = s;
        }
        // batched wave-wide sum: 6 steps x BATCH independent adds (ILP),
        // per-row tree order identical to baseline
        #pragma unroll
        for (int off = 32; off > 0; off >>= 1) {
            #pragma unroll
            for (int r = 0; r < BATCH; ++r)
                acc[r] += __shfl_down(acc[r], off, 64);
        }
        if (lane == 0) {
            #pragma unroll
            for (int r = 0; r < BATCH; ++r) {
                float d = sqrtf(acc[r]);   // d >= 0 -> float bits order-preserving
                unsigned long long enc =
                    ((unsigned long long)__float_as_uint(d) << 32) |
                    (unsigned)(waveRow0 + b + r);
                best = best < enc ? best : enc;
            }
        }
    }

    __shared__ unsigned long long sm[4];
    if (lane == 0) sm[wave] = best;
    __syncthreads();
    if (threadIdx.x == 0) {
        unsigned long long v = sm[0];
        #pragma unroll
        for (int i = 1; i < 4; ++i) v = v < sm[i] ? v : sm[i];
        part[blockIdx.x] = v;
    }
}

// ---------------- Kernel 2: reduce DIST_BLOCKS partials -> winner at part[DIST_BLOCKS] ----------------
__global__ __launch_bounds__(256) void som_reduce(unsigned long long* __restrict__ part)
{
    __shared__ unsigned long long sm[256];
    unsigned long long b = ~0ull;
    for (int i = threadIdx.x; i < DIST_BLOCKS; i += 256) {
        unsigned long long v = part[i];
        b = b < v ? b : v;
    }
    sm[threadIdx.x] = b;
    __syncthreads();
    #pragma unroll
    for (int s = 128; s > 0; s >>= 1) {
        if (threadIdx.x < s) {
            unsigned long long v = sm[threadIdx.x + s];
            if (v < sm[threadIdx.x]) sm[threadIdx.x] = v;
        }
        __syncthreads();
    }
    if (threadIdx.x == 0) part[DIST_BLOCKS] = sm[0];
}

// ---------------- Kernel 3: update weights (contiguous chunk / block, reverse order) ----------------
__global__ __launch_bounds__(256) void som_update(
    const float* __restrict__ x,
    const float* __restrict__ w,
    const int* __restrict__ loc,
    const int* __restrict__ itp,
    const unsigned long long* __restrict__ winner,
    float* __restrict__ out)
{
    const int tid = threadIdx.x;
    // reverse block mapping: freshest-in-L3 rows (highest addresses) first
    const int blk  = (UPD_BLOCKS - 1) - blockIdx.x;
    const int row0 = blk * ROWS_PER_UBLK;

    const int bmu = (int)(unsigned)(winner[DIST_BLOCKS] & 0xffffffffull);

    const float lr       = 1.0f - (float)itp[0] / NITERF;
    const float alpha_op = ALPHA * lr;
    const float sigma_op = SIGMA * lr;
    const float inv_s2   = 1.0f / (sigma_op * sigma_op);

    const float4 xq = ((const float4*)x)[tid];   // 256 threads cover a row's 256 float4

    for (int r = ROWS_PER_UBLK - 1; r >= 0; --r) {
        const int row = row0 + r;
        const float dloc  = (float)(loc[row] - bmu);     // wave-uniform
        const float neigh = expf(-(dloc * dloc) * inv_s2);
        const float lrm   = alpha_op * neigh;

        const float4 wv = ((const float4*)(w + (size_t)row * DIM))[tid];
        nfloat4 o;
        o.x = fmaf(lrm, xq.x - wv.x, wv.x);
        o.y = fmaf(lrm, xq.y - wv.y, wv.y);
        o.z = fmaf(lrm, xq.z - wv.z, wv.z);
        o.w = fmaf(lrm, xq.w - wv.w, wv.w);
        // nontemporal: out is never re-read; keep w resident in L3 instead
        __builtin_nontemporal_store(o, (nfloat4*)(out + (size_t)row * DIM) + tid);
    }
}

extern "C" void kernel_launch(void* const* d_in, const int* in_sizes, int n_in,
                              void* d_out, int out_size, void* d_ws, size_t ws_size,
                              hipStream_t stream)
{
    const float* x  = (const float*)d_in[0];
    const float* w  = (const float*)d_in[1];
    const int* loc  = (const int*)d_in[2];
    const int* itp  = (const int*)d_in[3];
    float* out      = (float*)d_out;
    unsigned long long* part = (unsigned long long*)d_ws;  // [DIST_BLOCKS] partials + [1] winner

    som_dist<<<DIST_BLOCKS, 256, 0, stream>>>(x, w, part);
    som_reduce<<<1, 256, 0, stream>>>(part);
    som_update<<<UPD_BLOCKS, 256, 0, stream>>>(x, w, loc, itp, part, out);
}